// Round 8
// baseline (770.411 us; speedup 1.0000x reference)
//
#include <hip/hip_runtime.h>
#include <stdint.h>

typedef unsigned short u16;
typedef __attribute__((ext_vector_type(8))) __bf16 bf16x8;
typedef __attribute__((ext_vector_type(4))) float f32x4;

#define NREL 7
#define DIM  512
#define DEDGE 59
#define KC   420     // NREL*59 + NREL (weight-sum columns)
#define KCP  448     // padded to multiple of 32
#define KTOT 4544    // NREL*512 (update) + 512 (self) + 448 (edge-G)

__device__ __forceinline__ float bf2f(u16 u) {
  union { unsigned u; float f; } c; c.u = ((unsigned)u) << 16; return c.f;
}
__device__ __forceinline__ u16 f2bf(float f) {
  union { float f; unsigned u; } c; c.f = f;
  unsigned r = ((c.u >> 16) & 1u) + 0x7FFFu;
  return (u16)((c.u + r) >> 16);
}

// ---- convert node_feat fp32 -> bf16 NF table [N,512] ----
__global__ void convA(const float* __restrict__ in, u16* __restrict__ out, int total4) {
  int i = blockIdx.x * 256 + threadIdx.x;
  if (i >= total4) return;
  float4 v = ((const float4*)in)[i];
  ushort4 r;
  r.x = f2bf(v.x); r.y = f2bf(v.y); r.z = f2bf(v.z); r.w = f2bf(v.w);
  ((ushort4*)out)[i] = r;
}

// ---- Bfull[o][k] bf16, [512][KTOT]: k<3584 -> W_lin[o][k]; 3584..4095 -> W_self[o][k-3584] ----
__global__ void buildBW(const float* __restrict__ W_lin, const float* __restrict__ W_self,
                        u16* __restrict__ Bfull, int total4) {
  int gid = blockIdx.x * 256 + threadIdx.x;
  if (gid >= total4) return;
  int idx = gid * 4;
  int o = idx >> 12;          // / 4096
  int k = idx & 4095;
  const float* src = (k < NREL * DIM) ? (W_lin + (size_t)o * (NREL * DIM) + k)
                                      : (W_self + (size_t)o * DIM + (k - NREL * DIM));
  float4 v = *(const float4*)src;
  ushort4 rr;
  rr.x = f2bf(v.x); rr.y = f2bf(v.y); rr.z = f2bf(v.z); rr.w = f2bf(v.w);
  *(ushort4*)(Bfull + (size_t)o * KTOT + k) = rr;
}

// ---- Bfull cols [4096, 4544): c=r*59+de -> sum_d W_edge[d,de]*W_lin[o,r*512+d];
//      c=413+r -> sum_d b_edge[d]*W_lin[o,r*512+d]; c>=420 -> 0 ----
__global__ __launch_bounds__(512) void buildCx(const float* __restrict__ W_edge,
                                               const float* __restrict__ b_edge,
                                               const float* __restrict__ W_lin,
                                               u16* __restrict__ Bfull) {
  int c = blockIdx.x;          // 0..447
  int o = threadIdx.x;         // 0..511
  u16* dst = Bfull + (size_t)o * KTOT + NREL * DIM + DIM;  // col base 4096
  if (c >= KC) { dst[c] = 0; return; }
  __shared__ float col[DIM];
  int r;
  if (c < NREL * DEDGE) {
    r = c / DEDGE;
    int de = c - r * DEDGE;
    col[o] = W_edge[(size_t)o * DEDGE + de];
  } else {
    r = c - NREL * DEDGE;
    col[o] = b_edge[o];
  }
  __syncthreads();
  const float* wrow = W_lin + (size_t)o * (NREL * DIM) + (size_t)r * DIM;
  float acc = 0.f;
#pragma unroll 8
  for (int d = 0; d < DIM; ++d) acc += col[d] * wrow[d];
  dst[c] = f2bf(acc);
}

// ---- two-level CSR keyed by (node_out, relation) ----
__global__ void countK2(const int* __restrict__ node_out, const int* __restrict__ relation,
                        int* __restrict__ counts2, int E) {
  int e = blockIdx.x * 256 + threadIdx.x;
  if (e < E) atomicAdd(&counts2[node_out[e] * 8 + relation[e]], 1);
}

__global__ void scanNode(const int* __restrict__ counts2, int* __restrict__ counts, int N) {
  int n = blockIdx.x * 256 + threadIdx.x;
  if (n >= N) return;
  int s = 0;
#pragma unroll
  for (int r = 0; r < NREL; ++r) s += counts2[n * 8 + r];
  counts[n] = s;
}

__global__ __launch_bounds__(1024) void scanK(const int* __restrict__ counts,
                                              int* __restrict__ offs, int n) {
  __shared__ int lds[1024];
  int tid = threadIdx.x;
  int carry = 0;
  for (int base = 0; base < n; base += 1024) {
    int i = base + tid;
    int v = (i < n) ? counts[i] : 0;
    lds[tid] = v;
    __syncthreads();
    for (int o = 1; o < 1024; o <<= 1) {
      int t = (tid >= o) ? lds[tid - o] : 0;
      __syncthreads();
      lds[tid] += t;
      __syncthreads();
    }
    int excl = lds[tid] - v;
    if (i < n) offs[i] = carry + excl;
    int total = lds[1023];
    carry += total;
    __syncthreads();
  }
  if (tid == 0) offs[n] = carry;
}

// per-node 8-slot prefix: offs2[n*8+r] = segment start; offs2[n*8+7] = node end
__global__ void offs2K(const int* __restrict__ offs, const int* __restrict__ counts2,
                       int* __restrict__ offs2, int* __restrict__ cursor2, int N) {
  int n = blockIdx.x * 256 + threadIdx.x;
  if (n >= N) return;
  int base = offs[n];
#pragma unroll
  for (int r = 0; r < NREL; ++r) {
    offs2[n * 8 + r] = base;
    cursor2[n * 8 + r] = base;
    base += counts2[n * 8 + r];
  }
  offs2[n * 8 + 7] = base;
}

__global__ void fillK2(const int* __restrict__ node_in, const int* __restrict__ node_out,
                       const int* __restrict__ relation, const float* __restrict__ ew,
                       int* __restrict__ cursor2, int* __restrict__ eids,
                       uint2* __restrict__ pairs, int E) {
  int e = blockIdx.x * 256 + threadIdx.x;
  if (e >= E) return;
  int p = atomicAdd(&cursor2[node_out[e] * 8 + relation[e]], 1);
  eids[p] = e;
  pairs[p] = make_uint2((unsigned)node_in[e], __float_as_uint(ew[e]));
}

// ---- edge-G aggregation (rel-segmented, atomic-free): Mfull cols [4096, 4544) ----
__global__ __launch_bounds__(64) void gatherG2(const float* __restrict__ ef,
                                               const int* __restrict__ eids,
                                               const uint2* __restrict__ pairs,
                                               const int* __restrict__ offs2,
                                               u16* __restrict__ Mfull) {
  int n = blockIdx.x;
  int lane = threadIdx.x;
  u16* row = Mfull + (size_t)n * KTOT + NREL * DIM + DIM;  // col 4096
  int base = n * 8;
  for (int r = 0; r < NREL; ++r) {
    int p0 = offs2[base + r], p1 = offs2[base + r + 1];
    float acc = 0.f;
    for (int p = p0; p < p1; ++p) {
      int e = __builtin_amdgcn_readfirstlane(eids[p]);
      float w = __uint_as_float(__builtin_amdgcn_readfirstlane(pairs[p].y));
      float v = (lane < DEDGE) ? ef[(size_t)e * DEDGE + lane] : 1.0f;
      acc += w * v;
    }
    if (lane < DEDGE) row[r * DEDGE + lane] = f2bf(acc);
    else if (lane == DEDGE) row[NREL * DEDGE + r] = f2bf(acc);
  }
  if (lane >= 60) {
    for (int c = KC + (lane - 60); c < KCP; c += 4) row[c] = 0;
  }
}

// ---- node-path aggregation from NF (20.5 MB, cache-hot) + self copy ----
__global__ __launch_bounds__(128) void aggK(const u16* __restrict__ NF,
                                            const uint2* __restrict__ pairs,
                                            const int* __restrict__ offs2,
                                            u16* __restrict__ Mfull) {
  int n = blockIdx.x;
  int o0 = threadIdx.x * 4;
  u16* mrow = Mfull + (size_t)n * KTOT;
  // self block: cols [3584, 4096)
  *(ushort4*)(mrow + NREL * DIM + o0) = *(const ushort4*)(NF + (size_t)n * DIM + o0);
  int base = n * 8;
  for (int r = 0; r < NREL; ++r) {
    int p0 = offs2[base + r], p1 = offs2[base + r + 1];
    float a0 = 0.f, a1 = 0.f, a2 = 0.f, a3 = 0.f;
    for (int p = p0; p < p1; ++p) {
      uint2 pr = pairs[p];
      int src = __builtin_amdgcn_readfirstlane((int)pr.x);
      float w = __uint_as_float(__builtin_amdgcn_readfirstlane(pr.y));
      ushort4 hv = *(const ushort4*)(NF + (size_t)src * DIM + o0);
      a0 += w * bf2f(hv.x);
      a1 += w * bf2f(hv.y);
      a2 += w * bf2f(hv.z);
      a3 += w * bf2f(hv.w);
    }
    ushort4 st;
    st.x = f2bf(a0); st.y = f2bf(a1); st.z = f2bf(a2); st.w = f2bf(a3);
    *(ushort4*)(mrow + r * DIM + o0) = st;
  }
}

// ---- fused MFMA GEMM, LDS-FREE: out[M,512] = relu(Mfull @ Bfull^T + b_lin + b_self)
//      Fragment loads go DIRECTLY global->VGPR: each wave-load covers 16 fully-used
//      64B lines (rows i*16+lr, 16B/lane) — L2-coalesced. No LDS, no barriers.
//      Manual register double-buffer (named X/Y sets, unroll-by-2; rule #20 safe).
//      Block 128x128, 4 waves, 64x64 wave tiles. XCD panel-grouping swizzle kept. ----
__global__ __launch_bounds__(256) void gemm_br(const u16* __restrict__ A,
                                               const u16* __restrict__ Bt,
                                               const float* __restrict__ b_lin,
                                               const float* __restrict__ b_self,
                                               float* __restrict__ Cout, int M) {
  const int tid = threadIdx.x;
  const int w = tid >> 6, l = tid & 63;
  const int lr = l & 15, kg = l >> 4;

  // panel-grouping swizzle: dispatch i -> XCD i%8; panel p's 4 column blocks on
  // the same XCD in consecutive slots. Bijective incl. tail (npan%8 != 0).
  const int id = blockIdx.x;
  const int npan = gridDim.x >> 2;
  const int nfull = (npan >> 3) << 3;
  int p, c;
  if (id < nfull * 4) {
    int g = id >> 5, r = id & 31;
    p = g * 8 + (r & 7);
    c = r >> 3;
  } else {
    int t = id - nfull * 4;
    p = nfull + (t >> 2);
    c = t & 3;
  }
  const int m0 = p * 128, n0 = c * 128;
  const int wr = w >> 1, wc = w & 1;

  // per-lane fragment base pointers (k advances by 32 elems = 64B per K-step)
  const u16* arow0; const u16* arow1; const u16* arow2; const u16* arow3;
  {
    int gm0 = m0 + wr * 64 + 0 * 16 + lr; gm0 = gm0 < M ? gm0 : M - 1;
    int gm1 = m0 + wr * 64 + 1 * 16 + lr; gm1 = gm1 < M ? gm1 : M - 1;
    int gm2 = m0 + wr * 64 + 2 * 16 + lr; gm2 = gm2 < M ? gm2 : M - 1;
    int gm3 = m0 + wr * 64 + 3 * 16 + lr; gm3 = gm3 < M ? gm3 : M - 1;
    arow0 = A + (size_t)gm0 * KTOT + kg * 8;
    arow1 = A + (size_t)gm1 * KTOT + kg * 8;
    arow2 = A + (size_t)gm2 * KTOT + kg * 8;
    arow3 = A + (size_t)gm3 * KTOT + kg * 8;
  }
  const u16* brow0 = Bt + (size_t)(n0 + wc * 64 + 0 * 16 + lr) * KTOT + kg * 8;
  const u16* brow1 = Bt + (size_t)(n0 + wc * 64 + 1 * 16 + lr) * KTOT + kg * 8;
  const u16* brow2 = Bt + (size_t)(n0 + wc * 64 + 2 * 16 + lr) * KTOT + kg * 8;
  const u16* brow3 = Bt + (size_t)(n0 + wc * 64 + 3 * 16 + lr) * KTOT + kg * 8;

  f32x4 acc[4][4];
  const f32x4 z4 = {0.f, 0.f, 0.f, 0.f};
#pragma unroll
  for (int i = 0; i < 4; ++i)
#pragma unroll
    for (int j = 0; j < 4; ++j) acc[i][j] = z4;

  const int ktiles = KTOT / 32;   // 142 (even)

  bf16x8 aX0, aX1, aX2, aX3, bX0, bX1, bX2, bX3;
  bf16x8 aY0, aY1, aY2, aY3, bY0, bY1, bY2, bY3;

  // preload kt=0 into X
  aX0 = *(const bf16x8*)(arow0); aX1 = *(const bf16x8*)(arow1);
  aX2 = *(const bf16x8*)(arow2); aX3 = *(const bf16x8*)(arow3);
  bX0 = *(const bf16x8*)(brow0); bX1 = *(const bf16x8*)(brow1);
  bX2 = *(const bf16x8*)(brow2); bX3 = *(const bf16x8*)(brow3);

#define MFMA_SET(AS0,AS1,AS2,AS3,BS0,BS1,BS2,BS3)                                   \
  acc[0][0] = __builtin_amdgcn_mfma_f32_16x16x32_bf16(AS0, BS0, acc[0][0], 0,0,0);  \
  acc[0][1] = __builtin_amdgcn_mfma_f32_16x16x32_bf16(AS0, BS1, acc[0][1], 0,0,0);  \
  acc[0][2] = __builtin_amdgcn_mfma_f32_16x16x32_bf16(AS0, BS2, acc[0][2], 0,0,0);  \
  acc[0][3] = __builtin_amdgcn_mfma_f32_16x16x32_bf16(AS0, BS3, acc[0][3], 0,0,0);  \
  acc[1][0] = __builtin_amdgcn_mfma_f32_16x16x32_bf16(AS1, BS0, acc[1][0], 0,0,0);  \
  acc[1][1] = __builtin_amdgcn_mfma_f32_16x16x32_bf16(AS1, BS1, acc[1][1], 0,0,0);  \
  acc[1][2] = __builtin_amdgcn_mfma_f32_16x16x32_bf16(AS1, BS2, acc[1][2], 0,0,0);  \
  acc[1][3] = __builtin_amdgcn_mfma_f32_16x16x32_bf16(AS1, BS3, acc[1][3], 0,0,0);  \
  acc[2][0] = __builtin_amdgcn_mfma_f32_16x16x32_bf16(AS2, BS0, acc[2][0], 0,0,0);  \
  acc[2][1] = __builtin_amdgcn_mfma_f32_16x16x32_bf16(AS2, BS1, acc[2][1], 0,0,0);  \
  acc[2][2] = __builtin_amdgcn_mfma_f32_16x16x32_bf16(AS2, BS2, acc[2][2], 0,0,0);  \
  acc[2][3] = __builtin_amdgcn_mfma_f32_16x16x32_bf16(AS2, BS3, acc[2][3], 0,0,0);  \
  acc[3][0] = __builtin_amdgcn_mfma_f32_16x16x32_bf16(AS3, BS0, acc[3][0], 0,0,0);  \
  acc[3][1] = __builtin_amdgcn_mfma_f32_16x16x32_bf16(AS3, BS1, acc[3][1], 0,0,0);  \
  acc[3][2] = __builtin_amdgcn_mfma_f32_16x16x32_bf16(AS3, BS2, acc[3][2], 0,0,0);  \
  acc[3][3] = __builtin_amdgcn_mfma_f32_16x16x32_bf16(AS3, BS3, acc[3][3], 0,0,0);

  for (int kt = 0; kt < ktiles; kt += 2) {
    const int o1 = (kt + 1) * 32;
    // load kt+1 into Y (issued before X's MFMAs -> latency hidden under them)
    aY0 = *(const bf16x8*)(arow0 + o1); aY1 = *(const bf16x8*)(arow1 + o1);
    aY2 = *(const bf16x8*)(arow2 + o1); aY3 = *(const bf16x8*)(arow3 + o1);
    bY0 = *(const bf16x8*)(brow0 + o1); bY1 = *(const bf16x8*)(brow1 + o1);
    bY2 = *(const bf16x8*)(brow2 + o1); bY3 = *(const bf16x8*)(brow3 + o1);
    MFMA_SET(aX0, aX1, aX2, aX3, bX0, bX1, bX2, bX3)
    if (kt + 2 < ktiles) {
      const int o2 = (kt + 2) * 32;
      aX0 = *(const bf16x8*)(arow0 + o2); aX1 = *(const bf16x8*)(arow1 + o2);
      aX2 = *(const bf16x8*)(arow2 + o2); aX3 = *(const bf16x8*)(arow3 + o2);
      bX0 = *(const bf16x8*)(brow0 + o2); bX1 = *(const bf16x8*)(brow1 + o2);
      bX2 = *(const bf16x8*)(brow2 + o2); bX3 = *(const bf16x8*)(brow3 + o2);
    }
    MFMA_SET(aY0, aY1, aY2, aY3, bY0, bY1, bY2, bY3)
  }
#undef MFMA_SET

  // epilogue: D col = lane&15, row = (lane>>4)*4 + v ; fuse bias + relu
#pragma unroll
  for (int i = 0; i < 4; ++i) {
#pragma unroll
    for (int j = 0; j < 4; ++j) {
      int gj = n0 + wc * 64 + j * 16 + lr;
      float bias = b_lin[gj] + b_self[gj];
#pragma unroll
      for (int v = 0; v < 4; ++v) {
        int gm = m0 + wr * 64 + i * 16 + kg * 4 + v;
        if (gm < M)
          ((float*)Cout)[(size_t)gm * DIM + gj] = fmaxf(acc[i][j][v] + bias, 0.f);
      }
    }
  }
}

extern "C" void kernel_launch(void* const* d_in, const int* in_sizes, int n_in,
                              void* d_out, int out_size, void* d_ws, size_t ws_size,
                              hipStream_t stream) {
  const float* node_feat = (const float*)d_in[0];
  const float* edge_weight = (const float*)d_in[1];
  const float* edge_feat = (const float*)d_in[2];
  const float* W_lin = (const float*)d_in[3];
  const float* b_lin = (const float*)d_in[4];
  const float* W_self = (const float*)d_in[5];
  const float* b_self = (const float*)d_in[6];
  const float* W_edge = (const float*)d_in[7];
  const float* b_edge = (const float*)d_in[8];
  const int* node_in = (const int*)d_in[9];
  const int* node_out = (const int*)d_in[10];
  const int* relation = (const int*)d_in[11];
  float* out = (float*)d_out;

  const int N = in_sizes[0] / DIM;
  const int E = in_sizes[1];

  char* ws = (char*)d_ws;
  size_t off = 0;
  auto take = [&](size_t b) {
    char* p = ws + off;
    off += (b + 255) & ~(size_t)255;
    return p;
  };
  u16* NF      = (u16*)take((size_t)N * DIM * 2);
  u16* Bfull   = (u16*)take((size_t)DIM * KTOT * 2);
  u16* Mfull   = (u16*)take((size_t)N * KTOT * 2);
  int* counts2 = (int*)take((size_t)N * 8 * 4);
  int* counts  = (int*)take((size_t)N * 4);
  int* offs    = (int*)take((size_t)(N + 1) * 4);
  int* offs2   = (int*)take((size_t)N * 8 * 4);
  int* cursor2 = (int*)take((size_t)N * 8 * 4);
  int* eids    = (int*)take((size_t)E * 4);
  uint2* pairs = (uint2*)take((size_t)E * 8);
  if (off > ws_size) return;  // workspace too small — fail visibly via absmax

  hipMemsetAsync(counts2, 0, (size_t)N * 8 * 4, stream);

  {
    int total4 = N * DIM / 4;
    convA<<<(total4 + 255) / 256, 256, 0, stream>>>(node_feat, NF, total4);
  }
  {
    int total4 = DIM * 4096 / 4;
    buildBW<<<(total4 + 255) / 256, 256, 0, stream>>>(W_lin, W_self, Bfull, total4);
  }
  buildCx<<<KCP, 512, 0, stream>>>(W_edge, b_edge, W_lin, Bfull);

  countK2<<<(E + 255) / 256, 256, 0, stream>>>(node_out, relation, counts2, E);
  scanNode<<<(N + 255) / 256, 256, 0, stream>>>(counts2, counts, N);
  scanK<<<1, 1024, 0, stream>>>(counts, offs, N);
  offs2K<<<(N + 255) / 256, 256, 0, stream>>>(offs, counts2, offs2, cursor2, N);
  fillK2<<<(E + 255) / 256, 256, 0, stream>>>(node_in, node_out, relation, edge_weight,
                                              cursor2, eids, pairs, E);

  // edge-G into Mfull cols [4096,4544)
  gatherG2<<<N, 64, 0, stream>>>(edge_feat, eids, pairs, offs2, Mfull);
  // node-path aggregation (cols [0,3584)) + self copy (cols [3584,4096))
  aggK<<<N, 128, 0, stream>>>(NF, pairs, offs2, Mfull);

  // single fused GEMM + bias + relu (1-D grid, swizzled in-kernel; LDS-free)
  {
    int npan = (N + 127) / 128;
    gemm_br<<<npan * 4, 256, 0, stream>>>(Mfull, Bfull, b_lin, b_self, out, N);
  }
}

// Round 9
// 490.270 us; speedup vs baseline: 1.5714x; 1.5714x over previous
//
#include <hip/hip_runtime.h>
#include <stdint.h>

typedef unsigned short u16;
typedef __attribute__((ext_vector_type(8))) __bf16 bf16x8;
typedef __attribute__((ext_vector_type(8))) unsigned short u16x8;
typedef __attribute__((ext_vector_type(4))) float f32x4;

#define NREL 7
#define DIM  512
#define DEDGE 59
#define KC   420     // NREL*59 + NREL (weight-sum columns)
#define KCP  448     // padded to multiple of 32
#define KTOT 4544    // NREL*512 (update) + 512 (self) + 448 (edge-G)

__device__ __forceinline__ float bf2f(u16 u) {
  union { unsigned u; float f; } c; c.u = ((unsigned)u) << 16; return c.f;
}
__device__ __forceinline__ u16 f2bf(float f) {
  union { float f; unsigned u; } c; c.f = f;
  unsigned r = ((c.u >> 16) & 1u) + 0x7FFFu;
  return (u16)((c.u + r) >> 16);
}

__device__ __forceinline__ void gload16(const void* g, void* l) {
  __builtin_amdgcn_global_load_lds(
      (__attribute__((address_space(1))) void*)g,
      (__attribute__((address_space(3))) void*)l, 16, 0, 0);
}

// ---- convert node_feat fp32 -> bf16 NF table [N,512] ----
__global__ void convA(const float* __restrict__ in, u16* __restrict__ out, int total4) {
  int i = blockIdx.x * 256 + threadIdx.x;
  if (i >= total4) return;
  float4 v = ((const float4*)in)[i];
  ushort4 r;
  r.x = f2bf(v.x); r.y = f2bf(v.y); r.z = f2bf(v.z); r.w = f2bf(v.w);
  ((ushort4*)out)[i] = r;
}

// ---- Bfull[o][k] bf16, [512][KTOT]: k<3584 -> W_lin[o][k]; 3584..4095 -> W_self[o][k-3584] ----
__global__ void buildBW(const float* __restrict__ W_lin, const float* __restrict__ W_self,
                        u16* __restrict__ Bfull, int total4) {
  int gid = blockIdx.x * 256 + threadIdx.x;
  if (gid >= total4) return;
  int idx = gid * 4;
  int o = idx >> 12;          // / 4096
  int k = idx & 4095;
  const float* src = (k < NREL * DIM) ? (W_lin + (size_t)o * (NREL * DIM) + k)
                                      : (W_self + (size_t)o * DIM + (k - NREL * DIM));
  float4 v = *(const float4*)src;
  ushort4 rr;
  rr.x = f2bf(v.x); rr.y = f2bf(v.y); rr.z = f2bf(v.z); rr.w = f2bf(v.w);
  *(ushort4*)(Bfull + (size_t)o * KTOT + k) = rr;
}

// ---- Bfull cols [4096, 4544): c=r*59+de -> sum_d W_edge[d,de]*W_lin[o,r*512+d];
//      c=413+r -> sum_d b_edge[d]*W_lin[o,r*512+d]; c>=420 -> 0 ----
__global__ __launch_bounds__(512) void buildCx(const float* __restrict__ W_edge,
                                               const float* __restrict__ b_edge,
                                               const float* __restrict__ W_lin,
                                               u16* __restrict__ Bfull) {
  int c = blockIdx.x;          // 0..447
  int o = threadIdx.x;         // 0..511
  u16* dst = Bfull + (size_t)o * KTOT + NREL * DIM + DIM;  // col base 4096
  if (c >= KC) { dst[c] = 0; return; }
  __shared__ float col[DIM];
  int r;
  if (c < NREL * DEDGE) {
    r = c / DEDGE;
    int de = c - r * DEDGE;
    col[o] = W_edge[(size_t)o * DEDGE + de];
  } else {
    r = c - NREL * DEDGE;
    col[o] = b_edge[o];
  }
  __syncthreads();
  const float* wrow = W_lin + (size_t)o * (NREL * DIM) + (size_t)r * DIM;
  float acc = 0.f;
#pragma unroll 8
  for (int d = 0; d < DIM; ++d) acc += col[d] * wrow[d];
  dst[c] = f2bf(acc);
}

// ---- two-level CSR keyed by (node_out, relation) ----
__global__ void countK2(const int* __restrict__ node_out, const int* __restrict__ relation,
                        int* __restrict__ counts2, int E) {
  int e = blockIdx.x * 256 + threadIdx.x;
  if (e < E) atomicAdd(&counts2[node_out[e] * 8 + relation[e]], 1);
}

// segment bases via atomic allocation — CSR segment ORDER is irrelevant (only
// disjointness matters), so no prefix scan needed. Replaces scanNode+scanK+offs2K.
__global__ void baseK(const int* __restrict__ counts2, int* __restrict__ offs2,
                      int* __restrict__ cursor2, int* __restrict__ totalCtr, int N) {
  int n = blockIdx.x * 256 + threadIdx.x;
  if (n >= N) return;
  int cnt[NREL];
  int s = 0;
#pragma unroll
  for (int r = 0; r < NREL; ++r) { cnt[r] = counts2[n * 8 + r]; s += cnt[r]; }
  int base = atomicAdd(totalCtr, s);
#pragma unroll
  for (int r = 0; r < NREL; ++r) {
    offs2[n * 8 + r] = base;
    cursor2[n * 8 + r] = base;
    base += cnt[r];
  }
  offs2[n * 8 + 7] = base;
}

// one 16B scattered store per edge: quad = (src, w_bits, e, 0)
__global__ void fillK2(const int* __restrict__ node_in, const int* __restrict__ node_out,
                       const int* __restrict__ relation, const float* __restrict__ ew,
                       int* __restrict__ cursor2, uint4* __restrict__ quads, int E) {
  int e = blockIdx.x * 256 + threadIdx.x;
  if (e >= E) return;
  int p = atomicAdd(&cursor2[node_out[e] * 8 + relation[e]], 1);
  quads[p] = make_uint4((unsigned)node_in[e], __float_as_uint(ew[e]), (unsigned)e, 0u);
}

// ---- edge-G aggregation (rel-segmented, atomic-free): Mfull cols [4096, 4544) ----
__global__ __launch_bounds__(64) void gatherG2(const float* __restrict__ ef,
                                               const uint4* __restrict__ quads,
                                               const int* __restrict__ offs2,
                                               u16* __restrict__ Mfull) {
  int n = blockIdx.x;
  int lane = threadIdx.x;
  u16* row = Mfull + (size_t)n * KTOT + NREL * DIM + DIM;  // col 4096
  int base = n * 8;
  for (int r = 0; r < NREL; ++r) {
    int p0 = offs2[base + r], p1 = offs2[base + r + 1];
    float acc = 0.f;
    for (int p = p0; p < p1; ++p) {
      uint4 q = quads[p];
      int e = __builtin_amdgcn_readfirstlane((int)q.z);
      float w = __uint_as_float(__builtin_amdgcn_readfirstlane(q.y));
      float v = (lane < DEDGE) ? ef[(size_t)e * DEDGE + lane] : 1.0f;
      acc += w * v;
    }
    if (lane < DEDGE) row[r * DEDGE + lane] = f2bf(acc);
    else if (lane == DEDGE) row[NREL * DEDGE + r] = f2bf(acc);
  }
  if (lane >= 60) {
    for (int c = KC + (lane - 60); c < KCP; c += 4) row[c] = 0;
  }
}

// ---- node-path aggregation from NF + self copy; 4 waves, relation-parallel:
//      wave wid handles r = wid, wid+4 (wave 3: r=3 + self copy). Lanes read
//      16B (ushort8) — 64 lanes cover the 512-wide row. ----
__global__ __launch_bounds__(256) void aggK(const u16* __restrict__ NF,
                                            const uint4* __restrict__ quads,
                                            const int* __restrict__ offs2,
                                            u16* __restrict__ Mfull) {
  int n = blockIdx.x;
  int wid = threadIdx.x >> 6, lane = threadIdx.x & 63;
  int o0 = lane * 8;
  u16* mrow = Mfull + (size_t)n * KTOT;
  if (wid == 3) {
    // self block: cols [3584, 4096)
    *(u16x8*)(mrow + NREL * DIM + o0) = *(const u16x8*)(NF + (size_t)n * DIM + o0);
  }
  int base = n * 8;
  for (int r = wid; r < NREL; r += 4) {
    int p0 = offs2[base + r], p1 = offs2[base + r + 1];
    float a[8];
#pragma unroll
    for (int j = 0; j < 8; ++j) a[j] = 0.f;
    for (int p = p0; p < p1; ++p) {
      uint4 q = quads[p];
      int src = __builtin_amdgcn_readfirstlane((int)q.x);
      float w = __uint_as_float(__builtin_amdgcn_readfirstlane(q.y));
      u16x8 hv = *(const u16x8*)(NF + (size_t)src * DIM + o0);
#pragma unroll
      for (int j = 0; j < 8; ++j) a[j] += w * bf2f(hv[j]);
    }
    u16x8 st;
#pragma unroll
    for (int j = 0; j < 8; ++j) st[j] = f2bf(a[j]);
    *(u16x8*)(mrow + r * DIM + o0) = st;
  }
}

// ---- fused MFMA GEMM: out[M,512] = relu(Mfull[M,KTOT] @ Bfull[512,KTOT]^T + b_lin + b_self)
//      R6 proven-best structure (150 us): T2 XOR bank-swizzle (conflicts=0),
//      3-buffer counted-vmcnt pipeline, XCD panel-grouping swizzle,
//      128x128 block, 4 waves, 64x64 wave tiles. ----
__global__ __launch_bounds__(256) void gemm_br(const u16* __restrict__ A,
                                               const u16* __restrict__ Bt,
                                               const float* __restrict__ b_lin,
                                               const float* __restrict__ b_self,
                                               float* __restrict__ Cout, int M) {
  __shared__ __align__(16) u16 sA[3][128 * 32];
  __shared__ __align__(16) u16 sB[3][128 * 32];
  const int tid = threadIdx.x;
  const int w = tid >> 6, l = tid & 63;
  const int lr = l & 15, kg = l >> 4;
  const int sl = kg ^ ((lr >> 1) & 3);   // swizzled 16B-slot to read (lane-constant)

  // panel-grouping swizzle: dispatch i -> XCD i%8; panel p's 4 column blocks on
  // the same XCD in consecutive slots. Bijective incl. tail (npan%8 != 0).
  const int id = blockIdx.x;
  const int npan = gridDim.x >> 2;
  const int nfull = (npan >> 3) << 3;
  int p, c;
  if (id < nfull * 4) {
    int g = id >> 5, r = id & 31;
    p = g * 8 + (r & 7);
    c = r >> 3;
  } else {
    int t = id - nfull * 4;
    p = nfull + (t >> 2);
    c = t & 3;
  }
  const int m0 = p * 128, n0 = c * 128;
  const int wr = w >> 1, wc = w & 1;
  f32x4 acc[4][4];
  const f32x4 z4 = {0.f, 0.f, 0.f, 0.f};
#pragma unroll
  for (int i = 0; i < 4; ++i)
#pragma unroll
    for (int j = 0; j < 4; ++j) acc[i][j] = z4;

  const int ktiles = KTOT / 32;   // 142

  // stage K-tile kt into buffer b: 4 global_load_lds per thread (2 A + 2 B).
  // LDS granule (row, kp) receives GLOBAL slot kp ^ ((row>>1)&3)  (pre-swizzle).
  auto stage = [&](int kt, int b) {
    const int k0 = kt * 32;
#pragma unroll
    for (int t = 0; t < 2; ++t) {
      int idx = w * 128 + t * 64 + l;     // 16B granule id within A tile (linear dest)
      int row = idx >> 2, kp = idx & 3;
      int s = kp ^ ((row >> 1) & 3);
      int gm = m0 + row; gm = gm < M ? gm : M - 1;
      gload16(A + (size_t)gm * KTOT + k0 + s * 8,
              (char*)sA[b] + (size_t)idx * 16);
    }
#pragma unroll
    for (int t = 0; t < 2; ++t) {
      int idx = w * 128 + t * 64 + l;
      int row = idx >> 2, kp = idx & 3;
      int s = kp ^ ((row >> 1) & 3);
      gload16(Bt + (size_t)(n0 + row) * KTOT + k0 + s * 8,
              (char*)sB[b] + (size_t)idx * 16);
    }
  };

  // prologue: fill depth-2 pipeline
  stage(0, 0);
  stage(1, 1);
  asm volatile("s_waitcnt vmcnt(4)" ::: "memory");   // stage(0) landed, stage(1) in flight
  __builtin_amdgcn_s_barrier();
  __builtin_amdgcn_sched_barrier(0);

  for (int kt = 0; kt < ktiles; ++kt) {
    const int cur = kt % 3;
    if (kt + 2 < ktiles) stage(kt + 2, (kt + 2) % 3);   // keep 2 tiles in flight
    bf16x8 af[4], bfr[4];
#pragma unroll
    for (int i = 0; i < 4; ++i)
      af[i] = *(const bf16x8*)(sA[cur] + (size_t)(wr * 64 + i * 16 + lr) * 32 + sl * 8);
#pragma unroll
    for (int j = 0; j < 4; ++j)
      bfr[j] = *(const bf16x8*)(sB[cur] + (size_t)(wc * 64 + j * 16 + lr) * 32 + sl * 8);
#pragma unroll
    for (int i = 0; i < 4; ++i)
#pragma unroll
      for (int j = 0; j < 4; ++j)
        acc[i][j] = __builtin_amdgcn_mfma_f32_16x16x32_bf16(af[i], bfr[j], acc[i][j], 0, 0, 0);
    // counted wait: ensure stage(kt+1) landed (oldest beyond the newest 4 retired);
    // stage(kt+2) stays in flight across the barrier. Tail: drain.
    if (kt + 2 < ktiles) {
      asm volatile("s_waitcnt vmcnt(4)" ::: "memory");
    } else {
      asm volatile("s_waitcnt vmcnt(0)" ::: "memory");
    }
    __builtin_amdgcn_s_barrier();
    __builtin_amdgcn_sched_barrier(0);
  }
  // epilogue: D col = lane&15, row = (lane>>4)*4 + v ; fuse bias + relu
#pragma unroll
  for (int i = 0; i < 4; ++i) {
#pragma unroll
    for (int j = 0; j < 4; ++j) {
      int gj = n0 + wc * 64 + j * 16 + lr;
      float bias = b_lin[gj] + b_self[gj];
#pragma unroll
      for (int v = 0; v < 4; ++v) {
        int gm = m0 + wr * 64 + i * 16 + kg * 4 + v;
        if (gm < M)
          ((float*)Cout)[(size_t)gm * DIM + gj] = fmaxf(acc[i][j][v] + bias, 0.f);
      }
    }
  }
}

extern "C" void kernel_launch(void* const* d_in, const int* in_sizes, int n_in,
                              void* d_out, int out_size, void* d_ws, size_t ws_size,
                              hipStream_t stream) {
  const float* node_feat = (const float*)d_in[0];
  const float* edge_weight = (const float*)d_in[1];
  const float* edge_feat = (const float*)d_in[2];
  const float* W_lin = (const float*)d_in[3];
  const float* b_lin = (const float*)d_in[4];
  const float* W_self = (const float*)d_in[5];
  const float* b_self = (const float*)d_in[6];
  const float* W_edge = (const float*)d_in[7];
  const float* b_edge = (const float*)d_in[8];
  const int* node_in = (const int*)d_in[9];
  const int* node_out = (const int*)d_in[10];
  const int* relation = (const int*)d_in[11];
  float* out = (float*)d_out;

  const int N = in_sizes[0] / DIM;
  const int E = in_sizes[1];

  char* ws = (char*)d_ws;
  size_t off = 0;
  auto take = [&](size_t b) {
    char* p = ws + off;
    off += (b + 255) & ~(size_t)255;
    return p;
  };
  u16* NF       = (u16*)take((size_t)N * DIM * 2);
  u16* Bfull    = (u16*)take((size_t)DIM * KTOT * 2);
  u16* Mfull    = (u16*)take((size_t)N * KTOT * 2);
  int* counts2  = (int*)take((size_t)N * 8 * 4);
  int* offs2    = (int*)take((size_t)N * 8 * 4);
  int* cursor2  = (int*)take((size_t)N * 8 * 4);
  int* totalCtr = (int*)take(256);
  uint4* quads  = (uint4*)take((size_t)E * 16);
  if (off > ws_size) return;  // workspace too small — fail visibly via absmax

  hipMemsetAsync(counts2, 0, (size_t)N * 8 * 4, stream);
  hipMemsetAsync(totalCtr, 0, 256, stream);

  {
    int total4 = N * DIM / 4;
    convA<<<(total4 + 255) / 256, 256, 0, stream>>>(node_feat, NF, total4);
  }
  {
    int total4 = DIM * 4096 / 4;
    buildBW<<<(total4 + 255) / 256, 256, 0, stream>>>(W_lin, W_self, Bfull, total4);
  }
  buildCx<<<KCP, 512, 0, stream>>>(W_edge, b_edge, W_lin, Bfull);

  countK2<<<(E + 255) / 256, 256, 0, stream>>>(node_out, relation, counts2, E);
  baseK<<<(N + 255) / 256, 256, 0, stream>>>(counts2, offs2, cursor2, totalCtr, N);
  fillK2<<<(E + 255) / 256, 256, 0, stream>>>(node_in, node_out, relation, edge_weight,
                                              cursor2, quads, E);

  // edge-G into Mfull cols [4096,4544)
  gatherG2<<<N, 64, 0, stream>>>(edge_feat, quads, offs2, Mfull);
  // node-path aggregation (cols [0,3584)) + self copy (cols [3584,4096))
  aggK<<<N, 256, 0, stream>>>(NF, quads, offs2, Mfull);

  // single fused GEMM + bias + relu (1-D grid, swizzled in-kernel)
  {
    int npan = (N + 127) / 128;
    gemm_br<<<npan * 4, 256, 0, stream>>>(Mfull, Bfull, b_lin, b_self, out, N);
  }
}